// Round 4
// baseline (2904.366 us; speedup 1.0000x reference)
//
#include <hip/hip_runtime.h>

#define NN 2048
#define BB 8
#define NITER 50
#define RPB 16                  // rows per block in fused kernel
#define CHUNKS (NN / RPB)       // 128

__device__ __forceinline__ float eps_f()      { return 0.01f; }
__device__ __forceinline__ float inv_eps_f()  { return 100.0f; }
// 0.01f * (-logf(2048.f))
__device__ __forceinline__ float eps_logmu_f(){ return -0.0762461898616f; }

// combine two (max, sum-of-exp-relative-to-max) pairs (arg scale = 1/eps)
__device__ __forceinline__ void lse_combine(float& m, float& s, float om, float os) {
    float M = fmaxf(m, om);
    s = s * __expf((m - M) * inv_eps_f()) + os * __expf((om - M) * inv_eps_f());
    m = M;
}

// ---------------- init: zero u, v ----------------
__global__ __launch_bounds__(256) void k_init(float* __restrict__ u, float* __restrict__ v) {
    int idx = blockIdx.x * 256 + threadIdx.x;
    if (idx < BB * NN) { u[idx] = 0.0f; v[idx] = 0.0f; }
}

// ---------------- fused u update + v partials: ONE pass over c ----------------
// Whole 16-row chunk register-resident. Structure per block:
//   1) 32 up-front global_load_dwordx4 (16 rows x 2 float4/thread)
//   2) per row: wave-MAX butterfly (no exps) -> 8 exps vs wave max -> SUM butterfly
//      (16 independent chains -> ILP; lane0 writes per-wave (m,s) to LDS)
//   3) ONE barrier; 16 threads combine 4 wave-partials each -> u[r]; ONE barrier
//   4) column phase: z = x + u_r in registers; per-column max over 16 rows +
//      16 exps; the chunk's (M,S) IS the partial (no running rescale).
//      pm stores M - v_j  (column LSE is over c+u = (x - v) + u = z - v).
__global__ __launch_bounds__(256, 2) void k_uv(const float* __restrict__ c,
                                               const float* __restrict__ v,
                                               float* __restrict__ u,
                                               float* __restrict__ pm,
                                               float* __restrict__ ps) {
    int chunk = blockIdx.x;
    int b     = blockIdx.y;
    int t     = threadIdx.x;
    int wid   = t >> 6;
    int lane  = t & 63;

    const float4* vb = (const float4*)(v + (size_t)b * NN);
    float4 v0 = vb[t];
    float4 v1 = vb[t + 256];

    const float* cbase = c + ((size_t)b * NN + (size_t)chunk * RPB) * NN;

    // 1) load the whole chunk into registers
    float4 a0[RPB], a1[RPB];
#pragma unroll
    for (int r = 0; r < RPB; ++r) {
        const float4* row = (const float4*)(cbase + (size_t)r * NN);
        a0[r] = row[t];
        a1[r] = row[t + 256];
    }

    __shared__ float wm[RPB][4], ws[RPB][4], su[RPB];

    // 2) row LSE over j of (c + v_old), max-first
#pragma unroll
    for (int r = 0; r < RPB; ++r) {
        a0[r].x += v0.x; a0[r].y += v0.y; a0[r].z += v0.z; a0[r].w += v0.w;
        a1[r].x += v1.x; a1[r].y += v1.y; a1[r].z += v1.z; a1[r].w += v1.w;
        float m = fmaxf(fmaxf(fmaxf(a0[r].x, a0[r].y), fmaxf(a0[r].z, a0[r].w)),
                        fmaxf(fmaxf(a1[r].x, a1[r].y), fmaxf(a1[r].z, a1[r].w)));
#pragma unroll
        for (int off = 32; off; off >>= 1) m = fmaxf(m, __shfl_xor(m, off, 64));
        float s = __expf((a0[r].x - m) * inv_eps_f()) + __expf((a0[r].y - m) * inv_eps_f())
                + __expf((a0[r].z - m) * inv_eps_f()) + __expf((a0[r].w - m) * inv_eps_f())
                + __expf((a1[r].x - m) * inv_eps_f()) + __expf((a1[r].y - m) * inv_eps_f())
                + __expf((a1[r].z - m) * inv_eps_f()) + __expf((a1[r].w - m) * inv_eps_f());
#pragma unroll
        for (int off = 32; off; off >>= 1) s += __shfl_xor(s, off, 64);
        if (lane == 0) { wm[r][wid] = m; ws[r][wid] = s; }
    }
    __syncthreads();

    // 3) cross-wave combine: 16 threads, one row each
    if (t < RPB) {
        float M = fmaxf(fmaxf(wm[t][0], wm[t][1]), fmaxf(wm[t][2], wm[t][3]));
        float S = ws[t][0] * __expf((wm[t][0] - M) * inv_eps_f())
                + ws[t][1] * __expf((wm[t][1] - M) * inv_eps_f())
                + ws[t][2] * __expf((wm[t][2] - M) * inv_eps_f())
                + ws[t][3] * __expf((wm[t][3] - M) * inv_eps_f());
        float uv = eps_logmu_f() - M - eps_f() * __logf(S);
        su[t] = uv;
        u[(size_t)b * NN + (size_t)chunk * RPB + t] = uv;
    }
    __syncthreads();

    float ur[RPB];
#pragma unroll
    for (int r = 0; r < RPB; ++r) ur[r] = su[r];

    // 4) column phase: z = x + u_r in place, then per-column max + exp-sum
#pragma unroll
    for (int r = 0; r < RPB; ++r) {
        float urr = ur[r];
        a0[r].x += urr; a0[r].y += urr; a0[r].z += urr; a0[r].w += urr;
        a1[r].x += urr; a1[r].y += urr; a1[r].z += urr; a1[r].w += urr;
    }
    float M0 = a0[0].x, M1 = a0[0].y, M2 = a0[0].z, M3 = a0[0].w;
    float M4 = a1[0].x, M5 = a1[0].y, M6 = a1[0].z, M7 = a1[0].w;
#pragma unroll
    for (int r = 1; r < RPB; ++r) {
        M0 = fmaxf(M0, a0[r].x); M1 = fmaxf(M1, a0[r].y);
        M2 = fmaxf(M2, a0[r].z); M3 = fmaxf(M3, a0[r].w);
        M4 = fmaxf(M4, a1[r].x); M5 = fmaxf(M5, a1[r].y);
        M6 = fmaxf(M6, a1[r].z); M7 = fmaxf(M7, a1[r].w);
    }
    float S0 = 0.f, S1 = 0.f, S2 = 0.f, S3 = 0.f;
    float S4 = 0.f, S5 = 0.f, S6 = 0.f, S7 = 0.f;
#pragma unroll
    for (int r = 0; r < RPB; ++r) {
        S0 += __expf((a0[r].x - M0) * inv_eps_f());
        S1 += __expf((a0[r].y - M1) * inv_eps_f());
        S2 += __expf((a0[r].z - M2) * inv_eps_f());
        S3 += __expf((a0[r].w - M3) * inv_eps_f());
        S4 += __expf((a1[r].x - M4) * inv_eps_f());
        S5 += __expf((a1[r].y - M5) * inv_eps_f());
        S6 += __expf((a1[r].z - M6) * inv_eps_f());
        S7 += __expf((a1[r].w - M7) * inv_eps_f());
    }

    size_t o = (size_t)(b * CHUNKS + chunk) * NN;
    ((float4*)(pm + o))[t]       = make_float4(M0 - v0.x, M1 - v0.y, M2 - v0.z, M3 - v0.w);
    ((float4*)(pm + o))[t + 256] = make_float4(M4 - v1.x, M5 - v1.y, M6 - v1.z, M7 - v1.w);
    ((float4*)(ps + o))[t]       = make_float4(S0, S1, S2, S3);
    ((float4*)(ps + o))[t + 256] = make_float4(S4, S5, S6, S7);
}

// ---------------- v update, phase 2: combine partials ----------------
// Each block: 64 consecutive columns of one batch. 4 waves each combine a
// strided quarter of the CHUNKS partials (coalesced loads), then merge in LDS.
__global__ __launch_bounds__(256) void k_v_combine(const float* __restrict__ pm,
                                                   const float* __restrict__ ps,
                                                   float* __restrict__ v) {
    int blk  = blockIdx.x;
    int b    = blk / (NN / 64);
    int jb   = (blk % (NN / 64)) * 64;
    int t    = threadIdx.x;
    int wid  = t >> 6;
    int lane = t & 63;
    int j    = jb + lane;

    float m = -INFINITY, s = 0.0f;
    size_t base = (size_t)b * CHUNKS * NN + j;
    for (int r = wid; r < CHUNKS; r += 4) {
        size_t o = base + (size_t)r * NN;
        lse_combine(m, s, pm[o], ps[o]);
    }

    __shared__ float lm[4][64], ls[4][64];
    lm[wid][lane] = m; ls[wid][lane] = s;
    __syncthreads();
    if (t < 64) {
        m = lm[0][lane]; s = ls[0][lane];
#pragma unroll
        for (int w = 1; w < 4; ++w) lse_combine(m, s, lm[w][lane], ls[w][lane]);
        float val = eps_logmu_f() - m - eps_f() * __logf(s);
        if (val > 9e8f) val = 0.0f;   // reference's huge-value clamp (never fires in practice)
        v[(size_t)b * NN + j] = val;
    }
}

// ---------------- finalize: pi = exp((c+u+v)*100), negc = -c ----------------
__global__ __launch_bounds__(256) void k_final(const float* __restrict__ c,
                                               const float* __restrict__ u,
                                               const float* __restrict__ v,
                                               float* __restrict__ pi,
                                               float* __restrict__ negc) {
    unsigned q = blockIdx.x * 256 + threadIdx.x;     // float4 index
    unsigned e = q * 4;                               // element index
    unsigned b = e >> 22;                             // / (NN*NN)
    unsigned rem = e & (NN * NN - 1);
    unsigned i = rem >> 11;
    unsigned j = rem & (NN - 1);

    float4 cc = ((const float4*)c)[q];
    float ui = u[b * NN + i];
    const float* vp = v + b * NN + j;
    float4 vv = *(const float4*)vp;

    float4 p;
    p.x = __expf((cc.x + ui + vv.x) * inv_eps_f());
    p.y = __expf((cc.y + ui + vv.y) * inv_eps_f());
    p.z = __expf((cc.z + ui + vv.z) * inv_eps_f());
    p.w = __expf((cc.w + ui + vv.w) * inv_eps_f());
    ((float4*)pi)[q] = p;

    float4 nc = { -cc.x, -cc.y, -cc.z, -cc.w };
    ((float4*)negc)[q] = nc;
}

// ---------------- copy u, v to output ----------------
__global__ __launch_bounds__(256) void k_uv_out(const float* __restrict__ u,
                                                const float* __restrict__ v,
                                                float* __restrict__ ou,
                                                float* __restrict__ ov) {
    int idx = blockIdx.x * 256 + threadIdx.x;
    if (idx < BB * NN) { ou[idx] = u[idx]; ov[idx] = v[idx]; }
}

extern "C" void kernel_launch(void* const* d_in, const int* in_sizes, int n_in,
                              void* d_out, int out_size, void* d_ws, size_t ws_size,
                              hipStream_t stream) {
    const float* c = (const float*)d_in[0];
    float* out  = (float*)d_out;
    float* pi   = out;
    float* negc = out + (size_t)BB * NN * NN;
    float* ou   = out + 2 * (size_t)BB * NN * NN;
    float* ov   = ou + BB * NN;

    float* ws = (float*)d_ws;
    float* u  = ws;
    float* v  = ws + BB * NN;
    // Partials (2 x 8.4 MB) live in the negc output region during iterations;
    // negc itself is written only afterwards by k_final.
    float* pm = negc;
    float* ps = negc + (size_t)BB * CHUNKS * NN;

    k_init<<<(BB * NN) / 256, 256, 0, stream>>>(u, v);

    dim3 gF(CHUNKS, BB);
    for (int it = 0; it < NITER; ++it) {
        k_uv<<<gF, 256, 0, stream>>>(c, v, u, pm, ps);
        k_v_combine<<<(BB * NN) / 64, 256, 0, stream>>>(pm, ps, v);
    }

    unsigned n4 = (unsigned)((size_t)BB * NN * NN / 4);
    k_final<<<n4 / 256, 256, 0, stream>>>(c, u, v, pi, negc);
    k_uv_out<<<(BB * NN) / 256, 256, 0, stream>>>(u, v, ou, ov);
}

// Round 5
// 2464.583 us; speedup vs baseline: 1.1784x; 1.1784x over previous
//
#include <hip/hip_runtime.h>

#define NN 2048
#define BB 8
#define NITER 50
#define RPB 16                  // rows per block in fused kernel
#define CHUNKS (NN / RPB)       // 128
#define VC_COLS 32              // columns per combine block
#define VC_PARTS 8              // chunk partitions per column

__device__ __forceinline__ float eps_f()      { return 0.01f; }
__device__ __forceinline__ float inv_eps_f()  { return 100.0f; }
// 0.01f * (-logf(2048.f))
__device__ __forceinline__ float eps_logmu_f(){ return -0.0762461898616f; }

// combine two (max, sum-of-exp-relative-to-max) pairs (arg scale = 1/eps)
__device__ __forceinline__ void lse_combine(float& m, float& s, float om, float os) {
    float M = fmaxf(m, om);
    s = s * __expf((m - M) * inv_eps_f()) + os * __expf((om - M) * inv_eps_f());
    m = M;
}

// ---------------- init: zero u, v ----------------
__global__ __launch_bounds__(256) void k_init(float* __restrict__ u, float* __restrict__ v) {
    int idx = blockIdx.x * 256 + threadIdx.x;
    if (idx < BB * NN) { u[idx] = 0.0f; v[idx] = 0.0f; }
}

// ---------------- fused u update + v partials: ONE pass over c ----------------
// (unchanged from round 4 — single-variable experiment this round)
__global__ __launch_bounds__(256, 2) void k_uv(const float* __restrict__ c,
                                               const float* __restrict__ v,
                                               float* __restrict__ u,
                                               float* __restrict__ pm,
                                               float* __restrict__ ps) {
    int chunk = blockIdx.x;
    int b     = blockIdx.y;
    int t     = threadIdx.x;
    int wid   = t >> 6;
    int lane  = t & 63;

    const float4* vb = (const float4*)(v + (size_t)b * NN);
    float4 v0 = vb[t];
    float4 v1 = vb[t + 256];

    const float* cbase = c + ((size_t)b * NN + (size_t)chunk * RPB) * NN;

    // 1) load the whole chunk into registers
    float4 a0[RPB], a1[RPB];
#pragma unroll
    for (int r = 0; r < RPB; ++r) {
        const float4* row = (const float4*)(cbase + (size_t)r * NN);
        a0[r] = row[t];
        a1[r] = row[t + 256];
    }

    __shared__ float wm[RPB][4], ws[RPB][4], su[RPB];

    // 2) row LSE over j of (c + v_old), max-first
#pragma unroll
    for (int r = 0; r < RPB; ++r) {
        a0[r].x += v0.x; a0[r].y += v0.y; a0[r].z += v0.z; a0[r].w += v0.w;
        a1[r].x += v1.x; a1[r].y += v1.y; a1[r].z += v1.z; a1[r].w += v1.w;
        float m = fmaxf(fmaxf(fmaxf(a0[r].x, a0[r].y), fmaxf(a0[r].z, a0[r].w)),
                        fmaxf(fmaxf(a1[r].x, a1[r].y), fmaxf(a1[r].z, a1[r].w)));
#pragma unroll
        for (int off = 32; off; off >>= 1) m = fmaxf(m, __shfl_xor(m, off, 64));
        float s = __expf((a0[r].x - m) * inv_eps_f()) + __expf((a0[r].y - m) * inv_eps_f())
                + __expf((a0[r].z - m) * inv_eps_f()) + __expf((a0[r].w - m) * inv_eps_f())
                + __expf((a1[r].x - m) * inv_eps_f()) + __expf((a1[r].y - m) * inv_eps_f())
                + __expf((a1[r].z - m) * inv_eps_f()) + __expf((a1[r].w - m) * inv_eps_f());
#pragma unroll
        for (int off = 32; off; off >>= 1) s += __shfl_xor(s, off, 64);
        if (lane == 0) { wm[r][wid] = m; ws[r][wid] = s; }
    }
    __syncthreads();

    // 3) cross-wave combine: 16 threads, one row each
    if (t < RPB) {
        float M = fmaxf(fmaxf(wm[t][0], wm[t][1]), fmaxf(wm[t][2], wm[t][3]));
        float S = ws[t][0] * __expf((wm[t][0] - M) * inv_eps_f())
                + ws[t][1] * __expf((wm[t][1] - M) * inv_eps_f())
                + ws[t][2] * __expf((wm[t][2] - M) * inv_eps_f())
                + ws[t][3] * __expf((wm[t][3] - M) * inv_eps_f());
        float uv = eps_logmu_f() - M - eps_f() * __logf(S);
        su[t] = uv;
        u[(size_t)b * NN + (size_t)chunk * RPB + t] = uv;
    }
    __syncthreads();

    float ur[RPB];
#pragma unroll
    for (int r = 0; r < RPB; ++r) ur[r] = su[r];

    // 4) column phase: z = x + u_r in place, then per-column max + exp-sum
#pragma unroll
    for (int r = 0; r < RPB; ++r) {
        float urr = ur[r];
        a0[r].x += urr; a0[r].y += urr; a0[r].z += urr; a0[r].w += urr;
        a1[r].x += urr; a1[r].y += urr; a1[r].z += urr; a1[r].w += urr;
    }
    float M0 = a0[0].x, M1 = a0[0].y, M2 = a0[0].z, M3 = a0[0].w;
    float M4 = a1[0].x, M5 = a1[0].y, M6 = a1[0].z, M7 = a1[0].w;
#pragma unroll
    for (int r = 1; r < RPB; ++r) {
        M0 = fmaxf(M0, a0[r].x); M1 = fmaxf(M1, a0[r].y);
        M2 = fmaxf(M2, a0[r].z); M3 = fmaxf(M3, a0[r].w);
        M4 = fmaxf(M4, a1[r].x); M5 = fmaxf(M5, a1[r].y);
        M6 = fmaxf(M6, a1[r].z); M7 = fmaxf(M7, a1[r].w);
    }
    float S0 = 0.f, S1 = 0.f, S2 = 0.f, S3 = 0.f;
    float S4 = 0.f, S5 = 0.f, S6 = 0.f, S7 = 0.f;
#pragma unroll
    for (int r = 0; r < RPB; ++r) {
        S0 += __expf((a0[r].x - M0) * inv_eps_f());
        S1 += __expf((a0[r].y - M1) * inv_eps_f());
        S2 += __expf((a0[r].z - M2) * inv_eps_f());
        S3 += __expf((a0[r].w - M3) * inv_eps_f());
        S4 += __expf((a1[r].x - M4) * inv_eps_f());
        S5 += __expf((a1[r].y - M5) * inv_eps_f());
        S6 += __expf((a1[r].z - M6) * inv_eps_f());
        S7 += __expf((a1[r].w - M7) * inv_eps_f());
    }

    size_t o = (size_t)(b * CHUNKS + chunk) * NN;
    ((float4*)(pm + o))[t]       = make_float4(M0 - v0.x, M1 - v0.y, M2 - v0.z, M3 - v0.w);
    ((float4*)(pm + o))[t + 256] = make_float4(M4 - v1.x, M5 - v1.y, M6 - v1.z, M7 - v1.w);
    ((float4*)(ps + o))[t]       = make_float4(S0, S1, S2, S3);
    ((float4*)(ps + o))[t + 256] = make_float4(S4, S5, S6, S7);
}

// ---------------- v update, phase 2: combine partials (REWRITTEN) ----------------
// 512 blocks (2/CU). Block = 32 columns x 8 partitions; thread combines 16 chunks
// in 2 batched groups of 8: loads issued together (16 in flight, max-first, no
// exp in the scan), then ONE lse_combine per group. Dependent-chain depth 2
// instead of 32. Merge: shfl_xor(32) intra-wave, then LDS across the 4 waves.
__global__ __launch_bounds__(256) void k_v_combine(const float* __restrict__ pm,
                                                   const float* __restrict__ ps,
                                                   float* __restrict__ v) {
    int blk = blockIdx.x;            // b * 64 + jg
    int b   = blk >> 6;
    int jb  = (blk & 63) * VC_COLS;
    int t   = threadIdx.x;
    int cl  = t & 31;                // column within group
    int p   = (t >> 5) & 7;          // partition 0..7
    int j   = jb + cl;
    size_t base = (size_t)b * CHUNKS * NN + j;

    float m, s;
#pragma unroll
    for (int g = 0; g < 2; ++g) {
        float mv[8], sv[8];
#pragma unroll
        for (int k = 0; k < 8; ++k) {
            int r = p + (g * 8 + k) * VC_PARTS;        // chunk index
            mv[k] = pm[base + (size_t)r * NN];
        }
#pragma unroll
        for (int k = 0; k < 8; ++k) {
            int r = p + (g * 8 + k) * VC_PARTS;
            sv[k] = ps[base + (size_t)r * NN];
        }
        float gm = fmaxf(fmaxf(fmaxf(mv[0], mv[1]), fmaxf(mv[2], mv[3])),
                         fmaxf(fmaxf(mv[4], mv[5]), fmaxf(mv[6], mv[7])));
        float gs = sv[0] * __expf((mv[0] - gm) * inv_eps_f())
                 + sv[1] * __expf((mv[1] - gm) * inv_eps_f())
                 + sv[2] * __expf((mv[2] - gm) * inv_eps_f())
                 + sv[3] * __expf((mv[3] - gm) * inv_eps_f())
                 + sv[4] * __expf((mv[4] - gm) * inv_eps_f())
                 + sv[5] * __expf((mv[5] - gm) * inv_eps_f())
                 + sv[6] * __expf((mv[6] - gm) * inv_eps_f())
                 + sv[7] * __expf((mv[7] - gm) * inv_eps_f());
        if (g == 0) { m = gm; s = gs; }
        else        { lse_combine(m, s, gm, gs); }
    }

    // merge partition pairs: lanes l and l^32 hold partitions 2w and 2w+1
    {
        float om = __shfl_xor(m, 32, 64);
        float os = __shfl_xor(s, 32, 64);
        lse_combine(m, s, om, os);
    }
    __shared__ float lm[4][VC_COLS], ls[4][VC_COLS];
    int w = t >> 6;
    if ((t & 63) < 32) { lm[w][cl] = m; ls[w][cl] = s; }
    __syncthreads();
    if (t < VC_COLS) {
        float M = lm[0][t], S = ls[0][t];
#pragma unroll
        for (int ww = 1; ww < 4; ++ww) lse_combine(M, S, lm[ww][t], ls[ww][t]);
        float val = eps_logmu_f() - M - eps_f() * __logf(S);
        if (val > 9e8f) val = 0.0f;   // reference's huge-value clamp (never fires in practice)
        v[(size_t)b * NN + jb + t] = val;
    }
}

// ---------------- finalize: pi = exp((c+u+v)*100), negc = -c ----------------
__global__ __launch_bounds__(256) void k_final(const float* __restrict__ c,
                                               const float* __restrict__ u,
                                               const float* __restrict__ v,
                                               float* __restrict__ pi,
                                               float* __restrict__ negc) {
    unsigned q = blockIdx.x * 256 + threadIdx.x;     // float4 index
    unsigned e = q * 4;                               // element index
    unsigned b = e >> 22;                             // / (NN*NN)
    unsigned rem = e & (NN * NN - 1);
    unsigned i = rem >> 11;
    unsigned j = rem & (NN - 1);

    float4 cc = ((const float4*)c)[q];
    float ui = u[b * NN + i];
    const float* vp = v + b * NN + j;
    float4 vv = *(const float4*)vp;

    float4 p;
    p.x = __expf((cc.x + ui + vv.x) * inv_eps_f());
    p.y = __expf((cc.y + ui + vv.y) * inv_eps_f());
    p.z = __expf((cc.z + ui + vv.z) * inv_eps_f());
    p.w = __expf((cc.w + ui + vv.w) * inv_eps_f());
    ((float4*)pi)[q] = p;

    float4 nc = { -cc.x, -cc.y, -cc.z, -cc.w };
    ((float4*)negc)[q] = nc;
}

// ---------------- copy u, v to output ----------------
__global__ __launch_bounds__(256) void k_uv_out(const float* __restrict__ u,
                                                const float* __restrict__ v,
                                                float* __restrict__ ou,
                                                float* __restrict__ ov) {
    int idx = blockIdx.x * 256 + threadIdx.x;
    if (idx < BB * NN) { ou[idx] = u[idx]; ov[idx] = v[idx]; }
}

extern "C" void kernel_launch(void* const* d_in, const int* in_sizes, int n_in,
                              void* d_out, int out_size, void* d_ws, size_t ws_size,
                              hipStream_t stream) {
    const float* c = (const float*)d_in[0];
    float* out  = (float*)d_out;
    float* pi   = out;
    float* negc = out + (size_t)BB * NN * NN;
    float* ou   = out + 2 * (size_t)BB * NN * NN;
    float* ov   = ou + BB * NN;

    float* ws = (float*)d_ws;
    float* u  = ws;
    float* v  = ws + BB * NN;
    // Partials (2 x 8.4 MB) live in the negc output region during iterations;
    // negc itself is written only afterwards by k_final.
    float* pm = negc;
    float* ps = negc + (size_t)BB * CHUNKS * NN;

    k_init<<<(BB * NN) / 256, 256, 0, stream>>>(u, v);

    dim3 gF(CHUNKS, BB);
    for (int it = 0; it < NITER; ++it) {
        k_uv<<<gF, 256, 0, stream>>>(c, v, u, pm, ps);
        k_v_combine<<<BB * (NN / VC_COLS), 256, 0, stream>>>(pm, ps, v);
    }

    unsigned n4 = (unsigned)((size_t)BB * NN * NN / 4);
    k_final<<<n4 / 256, 256, 0, stream>>>(c, u, v, pi, negc);
    k_uv_out<<<(BB * NN) / 256, 256, 0, stream>>>(u, v, ou, ov);
}

// Round 6
// 2138.720 us; speedup vs baseline: 1.3580x; 1.1524x over previous
//
#include <hip/hip_runtime.h>

#define NN 2048
#define BB 8
#define NITER 50
#define RPB 8                   // rows per block in fused kernel (was 16)
#define CHUNKS (NN / RPB)       // 256
#define VC_COLS 32              // columns per combine block
#define VC_PARTS 8              // chunk partitions per column
#define VC_GROUPS (CHUNKS / VC_PARTS / 8)   // 4 batched groups of 8 chunks

__device__ __forceinline__ float eps_f()      { return 0.01f; }
__device__ __forceinline__ float inv_eps_f()  { return 100.0f; }
// 0.01f * (-logf(2048.f))
__device__ __forceinline__ float eps_logmu_f(){ return -0.0762461898616f; }

// combine two (max, sum-of-exp-relative-to-max) pairs (arg scale = 1/eps)
__device__ __forceinline__ void lse_combine(float& m, float& s, float om, float os) {
    float M = fmaxf(m, om);
    s = s * __expf((m - M) * inv_eps_f()) + os * __expf((om - M) * inv_eps_f());
    m = M;
}

// ---------------- init: zero u, v ----------------
__global__ __launch_bounds__(256) void k_init(float* __restrict__ u, float* __restrict__ v) {
    int idx = blockIdx.x * 256 + threadIdx.x;
    if (idx < BB * NN) { u[idx] = 0.0f; v[idx] = 0.0f; }
}

// ---------------- fused u update + v partials: ONE pass over c ----------------
// RPB=8 rows register-resident per block; __launch_bounds__(256,4) -> ~16
// waves/CU (4 resident blocks) for memory-latency hiding. Same structure as
// round 4/5: up-front loads, max-first row LSE, 2 barriers, column phase with
// per-column max over the chunk (pm stores M - v_j).
__global__ __launch_bounds__(256, 4) void k_uv(const float* __restrict__ c,
                                               const float* __restrict__ v,
                                               float* __restrict__ u,
                                               float* __restrict__ pm,
                                               float* __restrict__ ps) {
    int chunk = blockIdx.x;
    int b     = blockIdx.y;
    int t     = threadIdx.x;
    int wid   = t >> 6;
    int lane  = t & 63;

    const float4* vb = (const float4*)(v + (size_t)b * NN);
    float4 v0 = vb[t];
    float4 v1 = vb[t + 256];

    const float* cbase = c + ((size_t)b * NN + (size_t)chunk * RPB) * NN;

    // 1) load the whole chunk into registers
    float4 a0[RPB], a1[RPB];
#pragma unroll
    for (int r = 0; r < RPB; ++r) {
        const float4* row = (const float4*)(cbase + (size_t)r * NN);
        a0[r] = row[t];
        a1[r] = row[t + 256];
    }

    __shared__ float wm[RPB][4], ws[RPB][4], su[RPB];

    // 2) row LSE over j of (c + v_old), max-first
#pragma unroll
    for (int r = 0; r < RPB; ++r) {
        a0[r].x += v0.x; a0[r].y += v0.y; a0[r].z += v0.z; a0[r].w += v0.w;
        a1[r].x += v1.x; a1[r].y += v1.y; a1[r].z += v1.z; a1[r].w += v1.w;
        float m = fmaxf(fmaxf(fmaxf(a0[r].x, a0[r].y), fmaxf(a0[r].z, a0[r].w)),
                        fmaxf(fmaxf(a1[r].x, a1[r].y), fmaxf(a1[r].z, a1[r].w)));
#pragma unroll
        for (int off = 32; off; off >>= 1) m = fmaxf(m, __shfl_xor(m, off, 64));
        float s = __expf((a0[r].x - m) * inv_eps_f()) + __expf((a0[r].y - m) * inv_eps_f())
                + __expf((a0[r].z - m) * inv_eps_f()) + __expf((a0[r].w - m) * inv_eps_f())
                + __expf((a1[r].x - m) * inv_eps_f()) + __expf((a1[r].y - m) * inv_eps_f())
                + __expf((a1[r].z - m) * inv_eps_f()) + __expf((a1[r].w - m) * inv_eps_f());
#pragma unroll
        for (int off = 32; off; off >>= 1) s += __shfl_xor(s, off, 64);
        if (lane == 0) { wm[r][wid] = m; ws[r][wid] = s; }
    }
    __syncthreads();

    // 3) cross-wave combine: RPB threads, one row each
    if (t < RPB) {
        float M = fmaxf(fmaxf(wm[t][0], wm[t][1]), fmaxf(wm[t][2], wm[t][3]));
        float S = ws[t][0] * __expf((wm[t][0] - M) * inv_eps_f())
                + ws[t][1] * __expf((wm[t][1] - M) * inv_eps_f())
                + ws[t][2] * __expf((wm[t][2] - M) * inv_eps_f())
                + ws[t][3] * __expf((wm[t][3] - M) * inv_eps_f());
        float uv = eps_logmu_f() - M - eps_f() * __logf(S);
        su[t] = uv;
        u[(size_t)b * NN + (size_t)chunk * RPB + t] = uv;
    }
    __syncthreads();

    float ur[RPB];
#pragma unroll
    for (int r = 0; r < RPB; ++r) ur[r] = su[r];

    // 4) column phase: z = x + u_r in place, then per-column max + exp-sum
#pragma unroll
    for (int r = 0; r < RPB; ++r) {
        float urr = ur[r];
        a0[r].x += urr; a0[r].y += urr; a0[r].z += urr; a0[r].w += urr;
        a1[r].x += urr; a1[r].y += urr; a1[r].z += urr; a1[r].w += urr;
    }
    float M0 = a0[0].x, M1 = a0[0].y, M2 = a0[0].z, M3 = a0[0].w;
    float M4 = a1[0].x, M5 = a1[0].y, M6 = a1[0].z, M7 = a1[0].w;
#pragma unroll
    for (int r = 1; r < RPB; ++r) {
        M0 = fmaxf(M0, a0[r].x); M1 = fmaxf(M1, a0[r].y);
        M2 = fmaxf(M2, a0[r].z); M3 = fmaxf(M3, a0[r].w);
        M4 = fmaxf(M4, a1[r].x); M5 = fmaxf(M5, a1[r].y);
        M6 = fmaxf(M6, a1[r].z); M7 = fmaxf(M7, a1[r].w);
    }
    float S0 = 0.f, S1 = 0.f, S2 = 0.f, S3 = 0.f;
    float S4 = 0.f, S5 = 0.f, S6 = 0.f, S7 = 0.f;
#pragma unroll
    for (int r = 0; r < RPB; ++r) {
        S0 += __expf((a0[r].x - M0) * inv_eps_f());
        S1 += __expf((a0[r].y - M1) * inv_eps_f());
        S2 += __expf((a0[r].z - M2) * inv_eps_f());
        S3 += __expf((a0[r].w - M3) * inv_eps_f());
        S4 += __expf((a1[r].x - M4) * inv_eps_f());
        S5 += __expf((a1[r].y - M5) * inv_eps_f());
        S6 += __expf((a1[r].z - M6) * inv_eps_f());
        S7 += __expf((a1[r].w - M7) * inv_eps_f());
    }

    size_t o = (size_t)(b * CHUNKS + chunk) * NN;
    ((float4*)(pm + o))[t]       = make_float4(M0 - v0.x, M1 - v0.y, M2 - v0.z, M3 - v0.w);
    ((float4*)(pm + o))[t + 256] = make_float4(M4 - v1.x, M5 - v1.y, M6 - v1.z, M7 - v1.w);
    ((float4*)(ps + o))[t]       = make_float4(S0, S1, S2, S3);
    ((float4*)(ps + o))[t + 256] = make_float4(S4, S5, S6, S7);
}

// ---------------- v update, phase 2: combine partials ----------------
// 512 blocks (2/CU). Block = 32 columns x 8 partitions; thread combines 32
// chunks in 4 batched groups of 8 (loads issued together, max-first, ONE
// lse_combine per group -> dependent-chain depth 4). Merge: shfl_xor(32)
// intra-wave, then LDS across the 4 waves.
__global__ __launch_bounds__(256) void k_v_combine(const float* __restrict__ pm,
                                                   const float* __restrict__ ps,
                                                   float* __restrict__ v) {
    int blk = blockIdx.x;            // b * 64 + jg
    int b   = blk >> 6;
    int jb  = (blk & 63) * VC_COLS;
    int t   = threadIdx.x;
    int cl  = t & 31;                // column within group
    int p   = (t >> 5) & 7;          // partition 0..7
    int j   = jb + cl;
    size_t base = (size_t)b * CHUNKS * NN + j;

    float m, s;
#pragma unroll
    for (int g = 0; g < VC_GROUPS; ++g) {
        float mv[8], sv[8];
#pragma unroll
        for (int k = 0; k < 8; ++k) {
            int r = p + (g * 8 + k) * VC_PARTS;        // chunk index
            mv[k] = pm[base + (size_t)r * NN];
        }
#pragma unroll
        for (int k = 0; k < 8; ++k) {
            int r = p + (g * 8 + k) * VC_PARTS;
            sv[k] = ps[base + (size_t)r * NN];
        }
        float gm = fmaxf(fmaxf(fmaxf(mv[0], mv[1]), fmaxf(mv[2], mv[3])),
                         fmaxf(fmaxf(mv[4], mv[5]), fmaxf(mv[6], mv[7])));
        float gs = sv[0] * __expf((mv[0] - gm) * inv_eps_f())
                 + sv[1] * __expf((mv[1] - gm) * inv_eps_f())
                 + sv[2] * __expf((mv[2] - gm) * inv_eps_f())
                 + sv[3] * __expf((mv[3] - gm) * inv_eps_f())
                 + sv[4] * __expf((mv[4] - gm) * inv_eps_f())
                 + sv[5] * __expf((mv[5] - gm) * inv_eps_f())
                 + sv[6] * __expf((mv[6] - gm) * inv_eps_f())
                 + sv[7] * __expf((mv[7] - gm) * inv_eps_f());
        if (g == 0) { m = gm; s = gs; }
        else        { lse_combine(m, s, gm, gs); }
    }

    // merge partition pairs: lanes l and l^32 hold partitions 2w and 2w+1
    {
        float om = __shfl_xor(m, 32, 64);
        float os = __shfl_xor(s, 32, 64);
        lse_combine(m, s, om, os);
    }
    __shared__ float lm[4][VC_COLS], ls[4][VC_COLS];
    int w = t >> 6;
    if ((t & 63) < 32) { lm[w][cl] = m; ls[w][cl] = s; }
    __syncthreads();
    if (t < VC_COLS) {
        float M = lm[0][t], S = ls[0][t];
#pragma unroll
        for (int ww = 1; ww < 4; ++ww) lse_combine(M, S, lm[ww][t], ls[ww][t]);
        float val = eps_logmu_f() - M - eps_f() * __logf(S);
        if (val > 9e8f) val = 0.0f;   // reference's huge-value clamp (never fires in practice)
        v[(size_t)b * NN + jb + t] = val;
    }
}

// ---------------- finalize: pi = exp((c+u+v)*100), negc = -c ----------------
__global__ __launch_bounds__(256) void k_final(const float* __restrict__ c,
                                               const float* __restrict__ u,
                                               const float* __restrict__ v,
                                               float* __restrict__ pi,
                                               float* __restrict__ negc) {
    unsigned q = blockIdx.x * 256 + threadIdx.x;     // float4 index
    unsigned e = q * 4;                               // element index
    unsigned b = e >> 22;                             // / (NN*NN)
    unsigned rem = e & (NN * NN - 1);
    unsigned i = rem >> 11;
    unsigned j = rem & (NN - 1);

    float4 cc = ((const float4*)c)[q];
    float ui = u[b * NN + i];
    const float* vp = v + b * NN + j;
    float4 vv = *(const float4*)vp;

    float4 p;
    p.x = __expf((cc.x + ui + vv.x) * inv_eps_f());
    p.y = __expf((cc.y + ui + vv.y) * inv_eps_f());
    p.z = __expf((cc.z + ui + vv.z) * inv_eps_f());
    p.w = __expf((cc.w + ui + vv.w) * inv_eps_f());
    ((float4*)pi)[q] = p;

    float4 nc = { -cc.x, -cc.y, -cc.z, -cc.w };
    ((float4*)negc)[q] = nc;
}

// ---------------- copy u, v to output ----------------
__global__ __launch_bounds__(256) void k_uv_out(const float* __restrict__ u,
                                                const float* __restrict__ v,
                                                float* __restrict__ ou,
                                                float* __restrict__ ov) {
    int idx = blockIdx.x * 256 + threadIdx.x;
    if (idx < BB * NN) { ou[idx] = u[idx]; ov[idx] = v[idx]; }
}

extern "C" void kernel_launch(void* const* d_in, const int* in_sizes, int n_in,
                              void* d_out, int out_size, void* d_ws, size_t ws_size,
                              hipStream_t stream) {
    const float* c = (const float*)d_in[0];
    float* out  = (float*)d_out;
    float* pi   = out;
    float* negc = out + (size_t)BB * NN * NN;
    float* ou   = out + 2 * (size_t)BB * NN * NN;
    float* ov   = ou + BB * NN;

    float* ws = (float*)d_ws;
    float* u  = ws;
    float* v  = ws + BB * NN;
    // Partials (2 x 16.8 MB) live in the negc output region during iterations;
    // negc itself is written only afterwards by k_final. (134 MB region, fits.)
    float* pm = negc;
    float* ps = negc + (size_t)BB * CHUNKS * NN;

    k_init<<<(BB * NN) / 256, 256, 0, stream>>>(u, v);

    dim3 gF(CHUNKS, BB);
    for (int it = 0; it < NITER; ++it) {
        k_uv<<<gF, 256, 0, stream>>>(c, v, u, pm, ps);
        k_v_combine<<<BB * (NN / VC_COLS), 256, 0, stream>>>(pm, ps, v);
    }

    unsigned n4 = (unsigned)((size_t)BB * NN * NN / 4);
    k_final<<<n4 / 256, 256, 0, stream>>>(c, u, v, pi, negc);
    k_uv_out<<<(BB * NN) / 256, 256, 0, stream>>>(u, v, ou, ov);
}

// Round 7
// 2060.077 us; speedup vs baseline: 1.4098x; 1.0382x over previous
//
#include <hip/hip_runtime.h>

#define NN 2048
#define BB 8
#define NITER 50
#define RPB 8                   // rows per register-resident slab
#define SLABS 2                 // slabs per block (sequential, LDS-merged)
#define ROWS_PB (RPB * SLABS)   // 16 rows per block
#define PCHUNKS (NN / ROWS_PB)  // 128 partial chunks
#define VC_COLS 32              // columns per combine block
#define VC_PARTS 8              // chunk partitions per column
#define VC_GROUPS (PCHUNKS / VC_PARTS / 8)   // 2 batched groups of 8 chunks

__device__ __forceinline__ float eps_f()      { return 0.01f; }
__device__ __forceinline__ float inv_eps_f()  { return 100.0f; }
// 0.01f * (-logf(2048.f))
__device__ __forceinline__ float eps_logmu_f(){ return -0.0762461898616f; }

// combine two (max, sum-of-exp-relative-to-max) pairs (arg scale = 1/eps)
__device__ __forceinline__ void lse_combine(float& m, float& s, float om, float os) {
    float M = fmaxf(m, om);
    s = s * __expf((m - M) * inv_eps_f()) + os * __expf((om - M) * inv_eps_f());
    m = M;
}

// ---------------- init: zero u, v ----------------
__global__ __launch_bounds__(256) void k_init(float* __restrict__ u, float* __restrict__ v) {
    int idx = blockIdx.x * 256 + threadIdx.x;
    if (idx < BB * NN) { u[idx] = 0.0f; v[idx] = 0.0f; }
}

// ---------------- fused u update + v partials: ONE pass over c ----------------
// Two 8-row register slabs per block, merged through an LDS column accumulator:
// keeps round-6 register footprint (~120 VGPR -> 4 blocks/CU, grid 1024 fully
// resident) while halving partial-chunk count (256 -> 128) and partial traffic.
// Slab A's per-column (M,S) -> LDS (thread-private slots); slab B merges and
// writes the global partial. pm stores M_z - v_j (z = c+v+u; column LSE needs
// c+u, and subtracting v_j shifts max and elements equally, S unchanged).
__global__ __launch_bounds__(256, 4) void k_uv(const float* __restrict__ c,
                                               const float* __restrict__ v,
                                               float* __restrict__ u,
                                               float* __restrict__ pm,
                                               float* __restrict__ ps) {
    int pair = blockIdx.x;           // 0..PCHUNKS-1
    int b    = blockIdx.y;
    int t    = threadIdx.x;
    int wid  = t >> 6;
    int lane = t & 63;

    const float4* vb = (const float4*)(v + (size_t)b * NN);
    float4 v0 = vb[t];
    float4 v1 = vb[t + 256];

    __shared__ float wm[RPB][4], ws[RPB][4], su[RPB];
    __shared__ float4 colm[512], cols[512];   // per-column (M,S) accumulator, 16 KB

#pragma unroll
    for (int sl = 0; sl < SLABS; ++sl) {
        const float* cbase = c + ((size_t)b * NN + (size_t)(pair * ROWS_PB + sl * RPB)) * NN;

        // 1) load this slab into registers
        float4 a0[RPB], a1[RPB];
#pragma unroll
        for (int r = 0; r < RPB; ++r) {
            const float4* row = (const float4*)(cbase + (size_t)r * NN);
            a0[r] = row[t];
            a1[r] = row[t + 256];
        }

        // 2) row LSE over j of (c + v_old), max-first
#pragma unroll
        for (int r = 0; r < RPB; ++r) {
            a0[r].x += v0.x; a0[r].y += v0.y; a0[r].z += v0.z; a0[r].w += v0.w;
            a1[r].x += v1.x; a1[r].y += v1.y; a1[r].z += v1.z; a1[r].w += v1.w;
            float m = fmaxf(fmaxf(fmaxf(a0[r].x, a0[r].y), fmaxf(a0[r].z, a0[r].w)),
                            fmaxf(fmaxf(a1[r].x, a1[r].y), fmaxf(a1[r].z, a1[r].w)));
#pragma unroll
            for (int off = 32; off; off >>= 1) m = fmaxf(m, __shfl_xor(m, off, 64));
            float s = __expf((a0[r].x - m) * inv_eps_f()) + __expf((a0[r].y - m) * inv_eps_f())
                    + __expf((a0[r].z - m) * inv_eps_f()) + __expf((a0[r].w - m) * inv_eps_f())
                    + __expf((a1[r].x - m) * inv_eps_f()) + __expf((a1[r].y - m) * inv_eps_f())
                    + __expf((a1[r].z - m) * inv_eps_f()) + __expf((a1[r].w - m) * inv_eps_f());
#pragma unroll
            for (int off = 32; off; off >>= 1) s += __shfl_xor(s, off, 64);
            if (lane == 0) { wm[r][wid] = m; ws[r][wid] = s; }
        }
        __syncthreads();

        // 3) cross-wave combine: RPB threads, one row each
        if (t < RPB) {
            float M = fmaxf(fmaxf(wm[t][0], wm[t][1]), fmaxf(wm[t][2], wm[t][3]));
            float S = ws[t][0] * __expf((wm[t][0] - M) * inv_eps_f())
                    + ws[t][1] * __expf((wm[t][1] - M) * inv_eps_f())
                    + ws[t][2] * __expf((wm[t][2] - M) * inv_eps_f())
                    + ws[t][3] * __expf((wm[t][3] - M) * inv_eps_f());
            float uv = eps_logmu_f() - M - eps_f() * __logf(S);
            su[t] = uv;
            u[(size_t)b * NN + (size_t)(pair * ROWS_PB + sl * RPB) + t] = uv;
        }
        __syncthreads();

        float ur[RPB];
#pragma unroll
        for (int r = 0; r < RPB; ++r) ur[r] = su[r];

        // 4) column phase: z = x + u_r in place, then per-column max + exp-sum
#pragma unroll
        for (int r = 0; r < RPB; ++r) {
            float urr = ur[r];
            a0[r].x += urr; a0[r].y += urr; a0[r].z += urr; a0[r].w += urr;
            a1[r].x += urr; a1[r].y += urr; a1[r].z += urr; a1[r].w += urr;
        }
        float M0 = a0[0].x, M1 = a0[0].y, M2 = a0[0].z, M3 = a0[0].w;
        float M4 = a1[0].x, M5 = a1[0].y, M6 = a1[0].z, M7 = a1[0].w;
#pragma unroll
        for (int r = 1; r < RPB; ++r) {
            M0 = fmaxf(M0, a0[r].x); M1 = fmaxf(M1, a0[r].y);
            M2 = fmaxf(M2, a0[r].z); M3 = fmaxf(M3, a0[r].w);
            M4 = fmaxf(M4, a1[r].x); M5 = fmaxf(M5, a1[r].y);
            M6 = fmaxf(M6, a1[r].z); M7 = fmaxf(M7, a1[r].w);
        }
        float S0 = 0.f, S1 = 0.f, S2 = 0.f, S3 = 0.f;
        float S4 = 0.f, S5 = 0.f, S6 = 0.f, S7 = 0.f;
#pragma unroll
        for (int r = 0; r < RPB; ++r) {
            S0 += __expf((a0[r].x - M0) * inv_eps_f());
            S1 += __expf((a0[r].y - M1) * inv_eps_f());
            S2 += __expf((a0[r].z - M2) * inv_eps_f());
            S3 += __expf((a0[r].w - M3) * inv_eps_f());
            S4 += __expf((a1[r].x - M4) * inv_eps_f());
            S5 += __expf((a1[r].y - M5) * inv_eps_f());
            S6 += __expf((a1[r].z - M6) * inv_eps_f());
            S7 += __expf((a1[r].w - M7) * inv_eps_f());
        }

        if (sl == 0) {
            // stash slab-A column partials in thread-private LDS slots
            colm[t]       = make_float4(M0, M1, M2, M3);
            colm[t + 256] = make_float4(M4, M5, M6, M7);
            cols[t]       = make_float4(S0, S1, S2, S3);
            cols[t + 256] = make_float4(S4, S5, S6, S7);
        } else {
            // merge slab A (from LDS) into slab B, write global partial
            float4 am0 = colm[t], am1 = colm[t + 256];
            float4 as0 = cols[t], as1 = cols[t + 256];
            lse_combine(M0, S0, am0.x, as0.x);
            lse_combine(M1, S1, am0.y, as0.y);
            lse_combine(M2, S2, am0.z, as0.z);
            lse_combine(M3, S3, am0.w, as0.w);
            lse_combine(M4, S4, am1.x, as1.x);
            lse_combine(M5, S5, am1.y, as1.y);
            lse_combine(M6, S6, am1.z, as1.z);
            lse_combine(M7, S7, am1.w, as1.w);

            size_t o = (size_t)(b * PCHUNKS + pair) * NN;
            ((float4*)(pm + o))[t]       = make_float4(M0 - v0.x, M1 - v0.y, M2 - v0.z, M3 - v0.w);
            ((float4*)(pm + o))[t + 256] = make_float4(M4 - v1.x, M5 - v1.y, M6 - v1.z, M7 - v1.w);
            ((float4*)(ps + o))[t]       = make_float4(S0, S1, S2, S3);
            ((float4*)(ps + o))[t + 256] = make_float4(S4, S5, S6, S7);
        }
    }
}

// ---------------- v update, phase 2: combine partials ----------------
// 512 blocks (2/CU). Block = 32 columns x 8 partitions; thread combines 16
// chunks in 2 batched groups of 8 (loads issued together, max-first, ONE
// lse_combine per group -> dependent-chain depth 2). Merge: shfl_xor(32)
// intra-wave, then LDS across the 4 waves.
__global__ __launch_bounds__(256) void k_v_combine(const float* __restrict__ pm,
                                                   const float* __restrict__ ps,
                                                   float* __restrict__ v) {
    int blk = blockIdx.x;            // b * 64 + jg
    int b   = blk >> 6;
    int jb  = (blk & 63) * VC_COLS;
    int t   = threadIdx.x;
    int cl  = t & 31;                // column within group
    int p   = (t >> 5) & 7;          // partition 0..7
    int j   = jb + cl;
    size_t base = (size_t)b * PCHUNKS * NN + j;

    float m, s;
#pragma unroll
    for (int g = 0; g < VC_GROUPS; ++g) {
        float mv[8], sv[8];
#pragma unroll
        for (int k = 0; k < 8; ++k) {
            int r = p + (g * 8 + k) * VC_PARTS;        // chunk index
            mv[k] = pm[base + (size_t)r * NN];
        }
#pragma unroll
        for (int k = 0; k < 8; ++k) {
            int r = p + (g * 8 + k) * VC_PARTS;
            sv[k] = ps[base + (size_t)r * NN];
        }
        float gm = fmaxf(fmaxf(fmaxf(mv[0], mv[1]), fmaxf(mv[2], mv[3])),
                         fmaxf(fmaxf(mv[4], mv[5]), fmaxf(mv[6], mv[7])));
        float gs = sv[0] * __expf((mv[0] - gm) * inv_eps_f())
                 + sv[1] * __expf((mv[1] - gm) * inv_eps_f())
                 + sv[2] * __expf((mv[2] - gm) * inv_eps_f())
                 + sv[3] * __expf((mv[3] - gm) * inv_eps_f())
                 + sv[4] * __expf((mv[4] - gm) * inv_eps_f())
                 + sv[5] * __expf((mv[5] - gm) * inv_eps_f())
                 + sv[6] * __expf((mv[6] - gm) * inv_eps_f())
                 + sv[7] * __expf((mv[7] - gm) * inv_eps_f());
        if (g == 0) { m = gm; s = gs; }
        else        { lse_combine(m, s, gm, gs); }
    }

    // merge partition pairs: lanes l and l^32 hold partitions 2w and 2w+1
    {
        float om = __shfl_xor(m, 32, 64);
        float os = __shfl_xor(s, 32, 64);
        lse_combine(m, s, om, os);
    }
    __shared__ float lm[4][VC_COLS], ls[4][VC_COLS];
    int w = t >> 6;
    if ((t & 63) < 32) { lm[w][cl] = m; ls[w][cl] = s; }
    __syncthreads();
    if (t < VC_COLS) {
        float M = lm[0][t], S = ls[0][t];
#pragma unroll
        for (int ww = 1; ww < 4; ++ww) lse_combine(M, S, lm[ww][t], ls[ww][t]);
        float val = eps_logmu_f() - M - eps_f() * __logf(S);
        if (val > 9e8f) val = 0.0f;   // reference's huge-value clamp (never fires in practice)
        v[(size_t)b * NN + jb + t] = val;
    }
}

// ---------------- finalize: pi = exp((c+u+v)*100), negc = -c ----------------
__global__ __launch_bounds__(256) void k_final(const float* __restrict__ c,
                                               const float* __restrict__ u,
                                               const float* __restrict__ v,
                                               float* __restrict__ pi,
                                               float* __restrict__ negc) {
    unsigned q = blockIdx.x * 256 + threadIdx.x;     // float4 index
    unsigned e = q * 4;                               // element index
    unsigned b = e >> 22;                             // / (NN*NN)
    unsigned rem = e & (NN * NN - 1);
    unsigned i = rem >> 11;
    unsigned j = rem & (NN - 1);

    float4 cc = ((const float4*)c)[q];
    float ui = u[b * NN + i];
    const float* vp = v + b * NN + j;
    float4 vv = *(const float4*)vp;

    float4 p;
    p.x = __expf((cc.x + ui + vv.x) * inv_eps_f());
    p.y = __expf((cc.y + ui + vv.y) * inv_eps_f());
    p.z = __expf((cc.z + ui + vv.z) * inv_eps_f());
    p.w = __expf((cc.w + ui + vv.w) * inv_eps_f());
    ((float4*)pi)[q] = p;

    float4 nc = { -cc.x, -cc.y, -cc.z, -cc.w };
    ((float4*)negc)[q] = nc;
}

// ---------------- copy u, v to output ----------------
__global__ __launch_bounds__(256) void k_uv_out(const float* __restrict__ u,
                                                const float* __restrict__ v,
                                                float* __restrict__ ou,
                                                float* __restrict__ ov) {
    int idx = blockIdx.x * 256 + threadIdx.x;
    if (idx < BB * NN) { ou[idx] = u[idx]; ov[idx] = v[idx]; }
}

extern "C" void kernel_launch(void* const* d_in, const int* in_sizes, int n_in,
                              void* d_out, int out_size, void* d_ws, size_t ws_size,
                              hipStream_t stream) {
    const float* c = (const float*)d_in[0];
    float* out  = (float*)d_out;
    float* pi   = out;
    float* negc = out + (size_t)BB * NN * NN;
    float* ou   = out + 2 * (size_t)BB * NN * NN;
    float* ov   = ou + BB * NN;

    float* ws = (float*)d_ws;
    float* u  = ws;
    float* v  = ws + BB * NN;
    // Partials (2 x 8.4 MB) live in the negc output region during iterations;
    // negc itself is written only afterwards by k_final. (134 MB region, fits.)
    float* pm = negc;
    float* ps = negc + (size_t)BB * PCHUNKS * NN;

    k_init<<<(BB * NN) / 256, 256, 0, stream>>>(u, v);

    dim3 gF(PCHUNKS, BB);                    // 1024 blocks = 4/CU, fully resident
    for (int it = 0; it < NITER; ++it) {
        k_uv<<<gF, 256, 0, stream>>>(c, v, u, pm, ps);
        k_v_combine<<<BB * (NN / VC_COLS), 256, 0, stream>>>(pm, ps, v);
    }

    unsigned n4 = (unsigned)((size_t)BB * NN * NN / 4);
    k_final<<<n4 / 256, 256, 0, stream>>>(c, u, v, pi, negc);
    k_uv_out<<<(BB * NN) / 256, 256, 0, stream>>>(u, v, ou, ov);
}